// Round 1
// baseline (1756.175 us; speedup 1.0000x reference)
//
#include <hip/hip_runtime.h>

// NeuralFieldCosmo: per-edge MLP(3->32->32->256, LN+ReLU, tanh) -> [16x16] W,
// gather f = edge_features[in_edges], out_ch[o] = sum_i f[i]*W[o][i],
// scatter-mean over out_edges into N rows.

constexpr float LN_EPS   = 1e-5f;
constexpr float LOG2E_X2 = 2.8853900817779268f;  // 2*log2(e)

__device__ __forceinline__ float fast_tanh(float x) {
  // tanh(x) = 1 - 2/(exp(2x)+1); exp(2x) = 2^(2x*log2e). Handles +-inf correctly.
  float e = __builtin_amdgcn_exp2f(x * LOG2E_X2);
  return 1.0f - 2.0f * __builtin_amdgcn_rcpf(e + 1.0f);
}

__device__ __forceinline__ void ln_relu(float* h, const float* __restrict__ g,
                                        const float* __restrict__ be) {
  float m = 0.f;
#pragma unroll
  for (int j = 0; j < 32; ++j) m += h[j];
  m *= (1.0f / 32.0f);
  float v = 0.f;
#pragma unroll
  for (int j = 0; j < 32; ++j) { float d = h[j] - m; v += d * d; }
  v *= (1.0f / 32.0f);
  const float rs = rsqrtf(v + LN_EPS);
#pragma unroll
  for (int j = 0; j < 32; ++j) {
    float y = (h[j] - m) * rs * g[j] + be[j];
    h[j] = y > 0.f ? y : 0.f;
  }
}

__global__ __launch_bounds__(256, 4)
void nf_main(const int* __restrict__ in_edges,
             const int* __restrict__ out_edges,
             const float* __restrict__ edge_features,
             const float* __restrict__ coords,
             const float* __restrict__ W1, const float* __restrict__ b1,
             const float* __restrict__ g1, const float* __restrict__ be1,
             const float* __restrict__ W2, const float* __restrict__ b2,
             const float* __restrict__ g2, const float* __restrict__ be2,
             const float* __restrict__ W3, const float* __restrict__ b3,
             float* __restrict__ sums, int* __restrict__ counts, int E)
{
  // LDS-staged weights; W2/W3 transposed so per-output dot reads contiguous float4.
  __shared__ float sW1[96];
  __shared__ float sb1[32], sg1[32], sbe1[32];
  __shared__ float sW2T[32 * 32];          // sW2T[j*32+k] = W2[k][j]
  __shared__ float sb2[32], sg2[32], sbe2[32];
  __shared__ float sW3T[256 * 32];         // sW3T[j*32+k] = W3[k][j]
  __shared__ float sb3[256];

  const int t = threadIdx.x;
  if (t < 96) sW1[t] = W1[t];
  if (t < 32) {
    sb1[t] = b1[t]; sg1[t] = g1[t]; sbe1[t] = be1[t];
    sb2[t] = b2[t]; sg2[t] = g2[t]; sbe2[t] = be2[t];
  }
  sb3[t] = b3[t];
#pragma unroll
  for (int i = 0; i < 4; ++i) {            // 1024 elems of W2T
    int idx = i * 256 + t;                 // idx = j*32+k
    sW2T[idx] = W2[(idx & 31) * 32 + (idx >> 5)];
  }
#pragma unroll
  for (int i = 0; i < 32; ++i) {           // 8192 elems of W3T
    int idx = i * 256 + t;                 // idx = j*32+k
    sW3T[idx] = W3[(idx & 31) * 256 + (idx >> 5)];
  }
  __syncthreads();

  const int stride = gridDim.x * blockDim.x;
  for (int e = blockIdx.x * blockDim.x + t; e < E; e += stride) {
    const float x0 = coords[3 * e + 0];
    const float x1 = coords[3 * e + 1];
    const float x2 = coords[3 * e + 2];

    // Layer 1: 3 -> 32, LN, ReLU
    float h[32];
#pragma unroll
    for (int j = 0; j < 32; ++j)
      h[j] = sb1[j] + x0 * sW1[j] + x1 * sW1[32 + j] + x2 * sW1[64 + j];
    ln_relu(h, sg1, sbe1);

    // Layer 2: 32 -> 32, LN, ReLU
    float h2[32];
#pragma unroll
    for (int j = 0; j < 32; ++j) {
      float a = sb2[j];
      const float4* r = (const float4*)&sW2T[j * 32];
#pragma unroll
      for (int k = 0; k < 8; ++k) {
        float4 w = r[k];
        a += h[4 * k + 0] * w.x + h[4 * k + 1] * w.y +
             h[4 * k + 2] * w.z + h[4 * k + 3] * w.w;
      }
      h2[j] = a;
    }
    ln_relu(h2, sg2, sbe2);

    // Gather f (16 floats, 4x float4)
    const int ie = in_edges[e];
    const float4* fp = (const float4*)(edge_features + (size_t)ie * 16);
    float4 f0 = fp[0], f1 = fp[1], f2 = fp[2], f3 = fp[3];
    float f[16] = {f0.x, f0.y, f0.z, f0.w, f1.x, f1.y, f1.z, f1.w,
                   f2.x, f2.y, f2.z, f2.w, f3.x, f3.y, f3.z, f3.w};

    // Layer 3 (32 -> 256) fused with tanh + per-edge matvec + scatter
    const int oe = out_edges[e];
    for (int o = 0; o < 16; ++o) {         // runtime loop: scalar accumulator
      float a = 0.f;
#pragma unroll
      for (int i = 0; i < 16; ++i) {       // unrolled: f[i], h2[*] static
        const int j = o * 16 + i;
        const float4* r = (const float4*)&sW3T[j * 32];
        float acc = sb3[j];
#pragma unroll
        for (int k = 0; k < 8; ++k) {
          float4 w = r[k];
          acc += h2[4 * k + 0] * w.x + h2[4 * k + 1] * w.y +
                 h2[4 * k + 2] * w.z + h2[4 * k + 3] * w.w;
        }
        a += f[i] * fast_tanh(acc);
      }
      atomicAdd(&sums[(size_t)oe * 16 + o], a);
    }
    atomicAdd(&counts[oe], 1);
  }
}

__global__ void nf_final(float* __restrict__ out, const int* __restrict__ counts, int n) {
  int i = blockIdx.x * blockDim.x + threadIdx.x;
  if (i < n) {
    float c = (float)counts[i >> 4];
    out[i] = out[i] / fmaxf(c, 1.0f);
  }
}

extern "C" void kernel_launch(void* const* d_in, const int* in_sizes, int n_in,
                              void* d_out, int out_size, void* d_ws, size_t ws_size,
                              hipStream_t stream) {
  const int*   in_edges  = (const int*)d_in[0];
  const int*   out_edges = (const int*)d_in[1];
  const float* ef        = (const float*)d_in[2];
  const float* coords    = (const float*)d_in[3];
  const float* W1  = (const float*)d_in[4];
  const float* b1  = (const float*)d_in[5];
  const float* g1  = (const float*)d_in[6];
  const float* be1 = (const float*)d_in[7];
  const float* W2  = (const float*)d_in[8];
  const float* b2  = (const float*)d_in[9];
  const float* g2  = (const float*)d_in[10];
  const float* be2 = (const float*)d_in[11];
  const float* W3  = (const float*)d_in[12];
  const float* b3  = (const float*)d_in[13];

  const int E = in_sizes[0];
  const int N = in_sizes[2] / 16;

  float* out    = (float*)d_out;
  int*   counts = (int*)d_ws;

  hipMemsetAsync(out, 0, (size_t)out_size * sizeof(float), stream);
  hipMemsetAsync(counts, 0, (size_t)N * sizeof(int), stream);

  nf_main<<<2048, 256, 0, stream>>>(in_edges, out_edges, ef, coords,
                                    W1, b1, g1, be1, W2, b2, g2, be2, W3, b3,
                                    out, counts, E);
  nf_final<<<(out_size + 255) / 256, 256, 0, stream>>>(out, counts, out_size);
}